// Round 1
// baseline (332.238 us; speedup 1.0000x reference)
//
#include <hip/hip_runtime.h>

// RoIPooling: img (1,512,512,256) f32, rois (1,256,4) i32 (x,y,w,h), w=h=28 fixed.
// out (1,256,7,7,256) f32: out[r,p,q,c] = max_{i,j in 0..3} img[0, x+4p+i, y+4q+j, c]
//
// Memory-bound gather: 205 MB read + 12.8 MB write -> ~35 us floor @ 6.3 TB/s.
// One 64-lane wave per (r,p,q) output position; lane l owns channels 4l..4l+3
// as a float4 -> each of the 16 pixel loads is one coalesced 1024 B transaction.

#define CH    256
#define IMW   512
#define CH4   (CH / 4)   // 64 float4 per pixel == one per lane

__global__ __launch_bounds__(64) void
roipool_kernel(const float* __restrict__ img,
               const int*   __restrict__ rois,
               float*       __restrict__ out) {
    const int bid = blockIdx.x;          // 0 .. R*49-1
    const int r   = bid / 49;
    const int pq  = bid - r * 49;
    const int p   = pq / 7;
    const int q   = pq - p * 7;

    // Block-uniform ROI coords -> scalar loads.
    const int x = rois[r * 4 + 0];       // row offset (dim 1)
    const int y = rois[r * 4 + 1];       // col offset (dim 2)

    const int lane = threadIdx.x;        // 0..63
    const int row0 = x + p * 4;
    const int col0 = y + q * 4;

    const float4* src = reinterpret_cast<const float4*>(img)
                      + ((size_t)row0 * IMW + col0) * CH4 + lane;

    float4 m = src[0];                   // (i=0, j=0)
#pragma unroll
    for (int i = 0; i < 4; ++i) {
        const float4* rp = src + (size_t)i * IMW * CH4;
#pragma unroll
        for (int j = 0; j < 4; ++j) {
            if (i == 0 && j == 0) continue;
            float4 v = rp[(size_t)j * CH4];
            m.x = fmaxf(m.x, v.x);
            m.y = fmaxf(m.y, v.y);
            m.z = fmaxf(m.z, v.z);
            m.w = fmaxf(m.w, v.w);
        }
    }

    reinterpret_cast<float4*>(out)[(size_t)bid * CH4 + lane] = m;
}

extern "C" void kernel_launch(void* const* d_in, const int* in_sizes, int n_in,
                              void* d_out, int out_size, void* d_ws, size_t ws_size,
                              hipStream_t stream) {
    const float* img  = (const float*)d_in[0];   // (1,512,512,256) f32
    const int*   rois = (const int*)  d_in[1];   // (1,256,4) i32
    float*       out  = (float*)d_out;           // (1,256,7,7,256) f32

    const int R = in_sizes[1] / 4;               // 256
    const int grid = R * 49;                     // one wave per (r,p,q)
    roipool_kernel<<<grid, 64, 0, stream>>>(img, rois, out);
}